// Round 14
// baseline (120.176 us; speedup 1.0000x reference)
//
#include <hip/hip_runtime.h>
#include <hip/hip_bf16.h>

#define BN 4096
#define DD 128

// All five bf16 matrices are pre-scaled by SQS = sqrt(2*log2(e)), so the
// MFMA dot product is directly the exp2 argument: 2^(SQS^2 * dot) = e^(2*dot).
#define SQS 1.69864356f

typedef __bf16 bf16x8 __attribute__((ext_vector_type(8)));
typedef float f32x16 __attribute__((ext_vector_type(16)));

#define RAW_BARRIER() asm volatile("s_barrier" ::: "memory")
#define WAIT_VM(N)    asm volatile("s_waitcnt vmcnt(" #N ")" ::: "memory")

__device__ __forceinline__ void gload_lds16(const void* g, void* l) {
    __builtin_amdgcn_global_load_lds(
        (const __attribute__((address_space(1))) void*)g,
        (__attribute__((address_space(3))) void*)l, 16, 0, 0);
}

__device__ __forceinline__ float fast_exp2(float x) {
    return __builtin_exp2f(x);
}

// ---------------- prep: f32 -> bf16 fragment-major (+gather), diag dots -----
// Fragment-major: per 32-row panel (8192 B), granule g = s*64 + h*32 + r
// holds row r, elements [16s+8h, 16s+8h+8).
__global__ __launch_bounds__(256) void prep_kernel(
    const float* __restrict__ z1, const float* __restrict__ z2,
    const float* __restrict__ attr, const int* __restrict__ uni,
    char* __restrict__ Z1f, char* __restrict__ Z2f,
    char* __restrict__ G1f, char* __restrict__ G2f, char* __restrict__ Af,
    float* __restrict__ d1, float* __restrict__ d2, float* __restrict__ d3,
    float* __restrict__ S1, float* __restrict__ S2, float* __restrict__ out)
{
    int p = blockIdx.x;        // half-panel 0..255 (16 rows each)
    int t = threadIdx.x;       // 0..255
    int gid = p * 256 + t;
    if (gid < 4 * BN) { S1[gid] = 0.f; S2[gid] = 0.f; }
    if (gid == 0) out[0] = 0.f;

    int r = t >> 4, q = t & 15;        // row-in-block (16), col-eighth (8 f32)
    int grow = p * 16 + r;
    int arow = uni[grow];

    __shared__ __hip_bfloat16 lp[5][16][128];

    const float* sp[5] = { z1 + (size_t)grow * DD, z2 + (size_t)grow * DD,
                           z1 + (size_t)arow * DD, z2 + (size_t)arow * DD,
                           attr + (size_t)arow * DD };
    float v[5][8];
    #pragma unroll
    for (int m = 0; m < 5; m++) {
        const float4* s4 = (const float4*)(sp[m] + q * 8);
        #pragma unroll
        for (int i = 0; i < 2; i++) {
            float4 f = s4[i];
            v[m][4*i+0] = f.x; v[m][4*i+1] = f.y;
            v[m][4*i+2] = f.z; v[m][4*i+3] = f.w;
        }
    }
    float p1 = 0.f, p2 = 0.f, p3 = 0.f;
    #pragma unroll
    for (int e = 0; e < 8; e++) {
        p3 += v[0][e] * v[1][e];
        p1 += v[2][e] * v[4][e];
        p2 += v[3][e] * v[4][e];
    }
    #pragma unroll
    for (int m = 1; m < 16; m <<= 1) {
        p1 += __shfl_xor(p1, m);
        p2 += __shfl_xor(p2, m);
        p3 += __shfl_xor(p3, m);
    }
    if (q == 0) { d1[grow] = p1; d2[grow] = p2; d3[grow] = p3; }

    #pragma unroll
    for (int m = 0; m < 5; m++)
        #pragma unroll
        for (int e = 0; e < 8; e++)
            lp[m][r][q * 8 + e] = __float2bfloat16(v[m][e] * SQS);
    __syncthreads();

    int panel = p >> 1, lo = (p & 1) * 16;
    char* dsts[5] = { Z1f, Z2f, G1f, G2f, Af };
    int s = t >> 5, h = (t >> 4) & 1, rl = t & 15;   // granule coords
    int g = s * 64 + h * 32 + lo + rl;
    #pragma unroll
    for (int m = 0; m < 5; m++) {
        bf16x8 val = *reinterpret_cast<const bf16x8*>(&lp[m][rl][s * 16 + h * 8]);
        *reinterpret_cast<bf16x8*>(dsts[m] + (size_t)panel * 8192 + (size_t)g * 16) = val;
    }
}

// ---------------- rowsum: raw-barrier pipelined fused sim + exp row-sum -----
// job 0: X=G1f vs Y=Af        chunks  0..7
// job 1: X=G2f vs Y=Af        chunks  8..15
// job 2: X=Z1f vs Y={Z1f,Z2f} chunks 16..31
// job 3: X=Z2f vs Y={Z1f,Z2f} chunks 32..47
// 4 waves x 64 X-rows = 256 rows/block; Y-chunk = 512 rows = 8 tiles of 64.
// SWAPPED MFMA operands (A=Y, B=X): Y-rowsum happens inside the accumulate,
// no shuffle tail; each yfrag ds_read feeds 2 MFMA chains (DS halved).
// SCHEDULE (the change vs r6/r11): NO __syncthreads. Per tile:
//   compute(buf b) ; s_barrier ; stage(buf b, t+2) ; vmcnt(4) ; s_barrier
// -- raw barriers carry no vmcnt(0)/lgkmcnt(0) drain, so the 2-tile-deep
// prefetch stays in flight across barriers (m97's per-barrier full drain was
// the serializer: measured 44us vs ~12us max-pipe bound).  vmcnt(4) = my 4
// stage-loads of tile t+1 done; barrier(2) makes that true block-wide.
__global__ __launch_bounds__(256) void rowsum_kernel(
    const char* __restrict__ Z1f, const char* __restrict__ Z2f,
    const char* __restrict__ G1f, const char* __restrict__ G2f,
    const char* __restrict__ Af,
    float* __restrict__ S1, float* __restrict__ S2)
{
    int rowblk = blockIdx.x;   // 0..15 : 256 X-rows each
    int chunk  = blockIdx.y;   // 0..47 : 512 Y-rows each

    int job;
    const char *X, *Y;
    int ybase;
    if (chunk < 8)       { job = 0; X = G1f; Y = Af; ybase = chunk * 512; }
    else if (chunk < 16) { job = 1; X = G2f; Y = Af; ybase = (chunk - 8) * 512; }
    else if (chunk < 32) { job = 2; X = Z1f; ybase = (chunk - 16) * 512;
                           Y = (ybase < BN) ? Z1f : Z2f; if (ybase >= BN) ybase -= BN; }
    else                 { job = 3; X = Z2f; ybase = (chunk - 32) * 512;
                           Y = (ybase < BN) ? Z1f : Z2f; if (ybase >= BN) ybase -= BN; }

    __shared__ char lds[2][16384];   // double-buffered 64-row Y tiles

    int tid  = threadIdx.x;
    int wid  = tid >> 6;      // 0..3
    int lane = tid & 63;
    int r = lane & 31, h = lane >> 5;
    size_t laneoff = (size_t)(h * 512 + r * 16);

    // B-operand: X fragments for TWO 32-row panels (64 X-rows per wave).
    int xblk = rowblk * 4 + wid;            // 64-row X block id (0..63)
    const char* xp = X + (size_t)(xblk * 2) * 8192 + laneoff;
    bf16x8 xb0[8], xb1[8];
    #pragma unroll
    for (int s = 0; s < 8; s++) {
        xb0[s] = *reinterpret_cast<const bf16x8*>(xp + s * 1024);
        xb1[s] = *reinterpret_cast<const bf16x8*>(xp + 8192 + s * 1024);
    }

    const char* Ychunk = Y + (size_t)ybase * 256;   // 8 tiles of 64 rows

    float a00 = 0.f, a01 = 0.f;   // X-group 0: sum e, sum e^2
    float a10 = 0.f, a11 = 0.f;   // X-group 1

    // Stage tile t (16 KB = 1024 granules) into buffer b: 4 gload_lds/thread.
    auto stage = [&](int b, int t) {
        const char* gsrc = Ychunk + (size_t)t * 16384 + (wid * 1024 + lane) * 16;
        char* dst = &lds[b][0] + wid * 4096;
        #pragma unroll
        for (int i = 0; i < 4; i++)
            gload_lds16(gsrc + i * 1024, dst + i * 1024);
    };

    // Consume one 64-row tile from buffer b.
    auto compute = [&](int b) {
        const char* tb = &lds[b][0] + laneoff;
        #pragma unroll
        for (int yg = 0; yg < 2; yg++) {
            f32x16 c0, c1;
            #pragma unroll
            for (int q = 0; q < 16; q++) { c0[q] = 0.f; c1[q] = 0.f; }
            #pragma unroll
            for (int s = 0; s < 8; s++) {
                bf16x8 yfrag = *reinterpret_cast<const bf16x8*>(tb + yg * 8192 + s * 1024);
                c0 = __builtin_amdgcn_mfma_f32_32x32x16_bf16(yfrag, xb0[s], c0, 0, 0, 0);
                c1 = __builtin_amdgcn_mfma_f32_32x32x16_bf16(yfrag, xb1[s], c1, 0, 0, 0);
            }
            // inputs pre-scaled: c = (2*log2 e)*dot -> e = e^(2*dot).
            #pragma unroll
            for (int q = 0; q < 16; q++) {
                float e0 = fast_exp2(c0[q]);
                a00 += e0;
                a01 = fmaf(e0, e0, a01);
                float e1 = fast_exp2(c1[q]);
                a10 += e1;
                a11 = fmaf(e1, e1, a11);
            }
        }
    };

    // Prologue: 2-deep prefetch; wait tile0 (my 4 oldest stage loads + X).
    stage(0, 0);
    stage(1, 1);
    WAIT_VM(4);
    RAW_BARRIER();

    #pragma unroll
    for (int t = 0; t < 8; t++) {
        compute(t & 1);
        RAW_BARRIER();                 // all waves done reading buf (t&1)
        if (t + 2 < 8) {
            stage(t & 1, t + 2);       // restage this buffer 2 tiles ahead
            WAIT_VM(4);                // my loads for tile t+1 done
        } else if (t + 1 < 8) {
            WAIT_VM(0);                // last prefetch (tile 7) done
        }
        if (t + 1 < 8) RAW_BARRIER();  // block-wide: tile t+1 ready
    }

    // Each lane holds partials for X-row xblk*64 + xg*32 + r; both h lanes
    // atomicAdd disjoint Y contributions.
    {
        int row0 = xblk * 64 + r;
        int row1 = xblk * 64 + 32 + r;
        atomicAdd(&S1[job * BN + row0], a00);
        atomicAdd(&S2[job * BN + row0], a01);
        atomicAdd(&S1[job * BN + row1], a10);
        atomicAdd(&S2[job * BN + row1], a11);
    }
}

// ---------------- finalize: per-row loss terms -> weighted mean --------------
__global__ __launch_bounds__(256) void finalize_kernel(
    const float* __restrict__ S1, const float* __restrict__ S2,
    const float* __restrict__ d1, const float* __restrict__ d2,
    const float* __restrict__ d3, float* __restrict__ out)
{
    int idx = blockIdx.x * 256 + threadIdx.x;   // 0..16383
    float term = 0.f;
    const float EM2 = 0.13533528323661270f;     // e^-2
    if (idx < 8192) {                           // inter jobs 0/1
        int j = idx >> 12, i = idx & 4095;
        float dv = j ? d2[i] : d1[i];
        float n = 4095.f;
        float pos = __expf(2.f * dv);
        float s1 = S1[j * BN + i] - pos;
        float s2 = S2[j * BN + i] - pos * pos;
        float rw = s2 * n / s1;
        float ng = (-0.1f * n * pos + rw) * (1.f / 0.9f);
        ng = fmaxf(ng, n * EM2);
        term = logf((pos + ng) / pos) * (0.5f / 4096.f);
    } else {                                    // intra rows 0..8191
        int i = idx - 8192;
        int ii = i & 4095;
        int job = 2 + (i >> 12);
        float n = 8190.f;
        const float E2 = 7.3890560989306495f, E4 = 54.598150033144236f;
        float pos = __expf(2.f * d3[ii]);
        float s1 = S1[job * BN + ii] - E2 - pos;
        float s2 = S2[job * BN + ii] - E4 - pos * pos;
        float rw = s2 * n / s1;
        float ng = (-0.1f * n * pos + rw) * (1.f / 0.9f);
        ng = fmaxf(ng, n * EM2);
        term = logf((pos + ng) / pos) * (1.f / 8192.f);
    }

    #pragma unroll
    for (int m = 1; m < 64; m <<= 1) term += __shfl_xor(term, m);
    __shared__ float sm[4];
    int wid = threadIdx.x >> 6;
    if ((threadIdx.x & 63) == 0) sm[wid] = term;
    __syncthreads();
    if (threadIdx.x == 0) atomicAdd(out, sm[0] + sm[1] + sm[2] + sm[3]);
}

extern "C" void kernel_launch(void* const* d_in, const int* in_sizes, int n_in,
                              void* d_out, int out_size, void* d_ws, size_t ws_size,
                              hipStream_t stream)
{
    const float* z1   = (const float*)d_in[0];
    const float* z2   = (const float*)d_in[1];
    // d_in[2] = text_z : unused by the reference
    const float* attr = (const float*)d_in[3];
    const int*   uni  = (const int*)d_in[4];
    float* out = (float*)d_out;

    char* ws = (char*)d_ws;
    size_t matb = (size_t)BN * DD * 2;               // bytes per bf16 matrix
    char* Z1f = ws;
    char* Z2f = Z1f + matb;
    char* G1f = Z2f + matb;
    char* G2f = G1f + matb;
    char* Af  = G2f + matb;
    float* S1 = (float*)(ws + 5 * matb);
    float* S2 = S1 + 4 * BN;
    float* d1 = S2 + 4 * BN;
    float* d2 = d1 + BN;
    float* d3 = d2 + BN;

    prep_kernel<<<256, 256, 0, stream>>>(z1, z2, attr, uni,
                                         Z1f, Z2f, G1f, G2f, Af,
                                         d1, d2, d3, S1, S2, out);
    rowsum_kernel<<<dim3(16, 48), 256, 0, stream>>>(Z1f, Z2f, G1f, G2f, Af, S1, S2);
    finalize_kernel<<<64, 256, 0, stream>>>(S1, S2, d1, d2, d3, out);
}

// Round 15
// 56.346 us; speedup vs baseline: 2.1328x; 2.1328x over previous
//
#include <hip/hip_runtime.h>
#include <hip/hip_bf16.h>

#define BN 4096
#define DD 128
#define NTILES 8   // 8 tiles x 64 cols = 512-col chunk per block

// All five bf16 matrices are pre-scaled by SQS = sqrt(2*log2(e)), so the
// MFMA dot product is directly the exp2 argument: 2^(SQS^2 * dot) = e^(2*dot).
#define SQS 1.69864356f

typedef __bf16 bf16x8 __attribute__((ext_vector_type(8)));
typedef float f32x16 __attribute__((ext_vector_type(16)));

#define RAW_BARRIER() asm volatile("s_barrier" ::: "memory")
#define WAIT_VM(N)    asm volatile("s_waitcnt vmcnt(" #N ")" ::: "memory")

__device__ __forceinline__ void gload_lds16(const void* g, void* l) {
    __builtin_amdgcn_global_load_lds(
        (const __attribute__((address_space(1))) void*)g,
        (__attribute__((address_space(3))) void*)l, 16, 0, 0);
}

__device__ __forceinline__ float fast_exp2(float x) {
    return __builtin_exp2f(x);
}

// ---------------- prep: f32 -> bf16 fragment-major (+gather), diag dots -----
// Fragment-major: per 32-row panel (8192 B), granule g = s*64 + h*32 + r
// holds row r, elements [16s+8h, 16s+8h+8).
__global__ __launch_bounds__(256) void prep_kernel(
    const float* __restrict__ z1, const float* __restrict__ z2,
    const float* __restrict__ attr, const int* __restrict__ uni,
    char* __restrict__ Z1f, char* __restrict__ Z2f,
    char* __restrict__ G1f, char* __restrict__ G2f, char* __restrict__ Af,
    float* __restrict__ d1, float* __restrict__ d2, float* __restrict__ d3,
    float* __restrict__ S1, float* __restrict__ S2, float* __restrict__ out)
{
    int p = blockIdx.x;        // half-panel 0..255 (16 rows each)
    int t = threadIdx.x;       // 0..255
    int gid = p * 256 + t;
    if (gid < 4 * BN) { S1[gid] = 0.f; S2[gid] = 0.f; }
    if (gid == 0) out[0] = 0.f;

    int r = t >> 4, q = t & 15;        // row-in-block (16), col-eighth (8 f32)
    int grow = p * 16 + r;
    int arow = uni[grow];

    __shared__ __hip_bfloat16 lp[5][16][128];

    const float* sp[5] = { z1 + (size_t)grow * DD, z2 + (size_t)grow * DD,
                           z1 + (size_t)arow * DD, z2 + (size_t)arow * DD,
                           attr + (size_t)arow * DD };
    float v[5][8];
    #pragma unroll
    for (int m = 0; m < 5; m++) {
        const float4* s4 = (const float4*)(sp[m] + q * 8);
        #pragma unroll
        for (int i = 0; i < 2; i++) {
            float4 f = s4[i];
            v[m][4*i+0] = f.x; v[m][4*i+1] = f.y;
            v[m][4*i+2] = f.z; v[m][4*i+3] = f.w;
        }
    }
    float p1 = 0.f, p2 = 0.f, p3 = 0.f;
    #pragma unroll
    for (int e = 0; e < 8; e++) {
        p3 += v[0][e] * v[1][e];
        p1 += v[2][e] * v[4][e];
        p2 += v[3][e] * v[4][e];
    }
    #pragma unroll
    for (int m = 1; m < 16; m <<= 1) {
        p1 += __shfl_xor(p1, m);
        p2 += __shfl_xor(p2, m);
        p3 += __shfl_xor(p3, m);
    }
    if (q == 0) { d1[grow] = p1; d2[grow] = p2; d3[grow] = p3; }

    #pragma unroll
    for (int m = 0; m < 5; m++)
        #pragma unroll
        for (int e = 0; e < 8; e++)
            lp[m][r][q * 8 + e] = __float2bfloat16(v[m][e] * SQS);
    __syncthreads();

    int panel = p >> 1, lo = (p & 1) * 16;
    char* dsts[5] = { Z1f, Z2f, G1f, G2f, Af };
    int s = t >> 5, h = (t >> 4) & 1, rl = t & 15;   // granule coords
    int g = s * 64 + h * 32 + lo + rl;
    #pragma unroll
    for (int m = 0; m < 5; m++) {
        bf16x8 val = *reinterpret_cast<const bf16x8*>(&lp[m][rl][s * 16 + h * 8]);
        *reinterpret_cast<bf16x8*>(dsts[m] + (size_t)panel * 8192 + (size_t)g * 16) = val;
    }
}

// ---------------- rowsum: fused sim + exp row-sum over 4 jobs ----------------
// job 0: X=G1f vs Y=Af        chunks  0..7
// job 1: X=G2f vs Y=Af        chunks  8..15
// job 2: X=Z1f vs Y={Z1f,Z2f} chunks 16..31
// job 3: X=Z2f vs Y={Z1f,Z2f} chunks 32..47
// Body identical to round 6 (best verified: VGPR 60, zero spill).  ONLY the
// synchronization changed: raw s_barrier + counted vmcnt replaces
// __syncthreads (whose implicit vmcnt(0) drained the just-issued prefetch
// every tile -- the serializer behind the 44us plateau, r2-r13).
// Schedule (2-deep prefetch; vmcnt never 0 mid-loop):
//   prologue: stage(buf0,t0); stage(buf1,t1)          // 8 loads in flight
//   loop ct:  WAIT_VM(4) [tile ct ready, newer 4 stay] ; s_barrier ;
//             compute(buf ct&1) ; s_barrier ; stage(buf ct&1, ct+2)
// Loop stays ROLLED (runtime cur via ternary pointer select -- rule #20
// kept: no runtime-indexed per-thread arrays; r14's full unroll hit 256
// VGPR + 277 MB spill and never tested the schedule).
__global__ __launch_bounds__(256, 4) void rowsum_kernel(
    const char* __restrict__ Z1f, const char* __restrict__ Z2f,
    const char* __restrict__ G1f, const char* __restrict__ G2f,
    const char* __restrict__ Af,
    float* __restrict__ S1, float* __restrict__ S2)
{
    int rowblk = blockIdx.x;   // 0..31 : 128 X-rows each
    int chunk  = blockIdx.y;   // 0..47 : 512 Y-rows each

    int job;
    const char *X, *Y;
    int ybase;
    if (chunk < 8)       { job = 0; X = G1f; Y = Af; ybase = chunk * 512; }
    else if (chunk < 16) { job = 1; X = G2f; Y = Af; ybase = (chunk - 8) * 512; }
    else if (chunk < 32) { job = 2; X = Z1f; ybase = (chunk - 16) * 512;
                           Y = (ybase < BN) ? Z1f : Z2f; if (ybase >= BN) ybase -= BN; }
    else                 { job = 3; X = Z2f; ybase = (chunk - 32) * 512;
                           Y = (ybase < BN) ? Z1f : Z2f; if (ybase >= BN) ybase -= BN; }

    __shared__ char lds0[16384];      // double-buffered 64-row Y tiles
    __shared__ char lds1[16384];

    int tid  = threadIdx.x;
    int wid  = tid >> 6;      // 0..3
    int lane = tid & 63;
    int r = lane & 31, h = lane >> 5;

    // A fragments from fragment-major X: panel px, addr s*1024 + h*512 + r*16
    int xrow0 = rowblk * 128 + wid * 32;
    int px = rowblk * 4 + wid;
    const char* xp = X + (size_t)px * 8192 + h * 512 + r * 16;
    bf16x8 afrag[8];
    #pragma unroll
    for (int s = 0; s < 8; s++)
        afrag[s] = *reinterpret_cast<const bf16x8*>(xp + s * 1024);

    const char* Ychunk = Y + (size_t)ybase * 256;   // panel-aligned (512 rows)

    float acc1[16], acc2[16];
    #pragma unroll
    for (int q = 0; q < 16; q++) { acc1[q] = 0.f; acc2[q] = 0.f; }

    auto stage = [&](char* dstbuf, int ct) {
        const char* gsrc = Ychunk + (size_t)ct * 16384;
        #pragma unroll
        for (int i = 0; i < 4; i++)
            gload_lds16(gsrc + wid * 4096 + i * 1024 + lane * 16,
                        dstbuf + wid * 4096 + i * 1024);
    };

    // Prologue: 2-deep prefetch (8 loads/thread in flight; X loads older).
    stage(lds0, 0);
    stage(lds1, 1);

    for (int ct = 0; ct < NTILES; ct++) {
        if (ct < NTILES - 1) { WAIT_VM(4); } else { WAIT_VM(0); }
        RAW_BARRIER();                    // tile ct visible block-wide
        char* buf = (ct & 1) ? lds1 : lds0;
        const char* tb = buf + lane * 16;
        #pragma unroll
        for (int G = 0; G < 2; G++) {                  // two 32-col groups
            f32x16 cacc;
            #pragma unroll
            for (int q = 0; q < 16; q++) cacc[q] = 0.f;
            #pragma unroll
            for (int s = 0; s < 8; s++) {
                bf16x8 bfrag = *reinterpret_cast<const bf16x8*>(tb + G * 8192 + s * 1024);
                cacc = __builtin_amdgcn_mfma_f32_32x32x16_bf16(afrag[s], bfrag, cacc, 0, 0, 0);
            }
            // inputs pre-scaled: cacc = (2*log2 e)*dot -> e1 = e^(2*dot)
            #pragma unroll
            for (int q = 0; q < 16; q++) {
                float e1 = fast_exp2(cacc[q]);
                acc1[q] += e1;
                acc2[q] = fmaf(e1, e1, acc2[q]);
            }
        }
        RAW_BARRIER();                    // all waves done reading buf
        if (ct + 2 < NTILES) stage(buf, ct + 2);   // refill freed buffer
    }

    // Reduce over the 32 lanes sharing each output row
    #pragma unroll
    for (int q = 0; q < 16; q++) {
        float a1 = acc1[q], a2 = acc2[q];
        #pragma unroll
        for (int m = 1; m < 32; m <<= 1) {
            a1 += __shfl_xor(a1, m);
            a2 += __shfl_xor(a2, m);
        }
        acc1[q] = a1; acc2[q] = a2;
    }
    if (r == 0) {
        // C/D layout: col = lane&31, row = (q&3) + 8*(q>>2) + 4*(lane>>5)
        #pragma unroll
        for (int q = 0; q < 16; q++) {
            int grow = xrow0 + (q & 3) + 8 * (q >> 2) + 4 * h;
            atomicAdd(&S1[job * BN + grow], acc1[q]);
            atomicAdd(&S2[job * BN + grow], acc2[q]);
        }
    }
}

// ---------------- finalize: per-row loss terms -> weighted mean --------------
__global__ __launch_bounds__(256) void finalize_kernel(
    const float* __restrict__ S1, const float* __restrict__ S2,
    const float* __restrict__ d1, const float* __restrict__ d2,
    const float* __restrict__ d3, float* __restrict__ out)
{
    int idx = blockIdx.x * 256 + threadIdx.x;   // 0..16383
    float term = 0.f;
    const float EM2 = 0.13533528323661270f;     // e^-2
    if (idx < 8192) {                           // inter jobs 0/1
        int j = idx >> 12, i = idx & 4095;
        float dv = j ? d2[i] : d1[i];
        float n = 4095.f;
        float pos = __expf(2.f * dv);
        float s1 = S1[j * BN + i] - pos;
        float s2 = S2[j * BN + i] - pos * pos;
        float rw = s2 * n / s1;
        float ng = (-0.1f * n * pos + rw) * (1.f / 0.9f);
        ng = fmaxf(ng, n * EM2);
        term = logf((pos + ng) / pos) * (0.5f / 4096.f);
    } else {                                    // intra rows 0..8191
        int i = idx - 8192;
        int ii = i & 4095;
        int job = 2 + (i >> 12);
        float n = 8190.f;
        const float E2 = 7.3890560989306495f, E4 = 54.598150033144236f;
        float pos = __expf(2.f * d3[ii]);
        float s1 = S1[job * BN + ii] - E2 - pos;
        float s2 = S2[job * BN + ii] - E4 - pos * pos;
        float rw = s2 * n / s1;
        float ng = (-0.1f * n * pos + rw) * (1.f / 0.9f);
        ng = fmaxf(ng, n * EM2);
        term = logf((pos + ng) / pos) * (1.f / 8192.f);
    }

    #pragma unroll
    for (int m = 1; m < 64; m <<= 1) term += __shfl_xor(term, m);
    __shared__ float sm[4];
    int wid = threadIdx.x >> 6;
    if ((threadIdx.x & 63) == 0) sm[wid] = term;
    __syncthreads();
    if (threadIdx.x == 0) atomicAdd(out, sm[0] + sm[1] + sm[2] + sm[3]);
}

extern "C" void kernel_launch(void* const* d_in, const int* in_sizes, int n_in,
                              void* d_out, int out_size, void* d_ws, size_t ws_size,
                              hipStream_t stream)
{
    const float* z1   = (const float*)d_in[0];
    const float* z2   = (const float*)d_in[1];
    // d_in[2] = text_z : unused by the reference
    const float* attr = (const float*)d_in[3];
    const int*   uni  = (const int*)d_in[4];
    float* out = (float*)d_out;

    char* ws = (char*)d_ws;
    size_t matb = (size_t)BN * DD * 2;               // bytes per bf16 matrix
    char* Z1f = ws;
    char* Z2f = Z1f + matb;
    char* G1f = Z2f + matb;
    char* G2f = G1f + matb;
    char* Af  = G2f + matb;
    float* S1 = (float*)(ws + 5 * matb);
    float* S2 = S1 + 4 * BN;
    float* d1 = S2 + 4 * BN;
    float* d2 = d1 + BN;
    float* d3 = d2 + BN;

    prep_kernel<<<256, 256, 0, stream>>>(z1, z2, attr, uni,
                                         Z1f, Z2f, G1f, G2f, Af,
                                         d1, d2, d3, S1, S2, out);
    rowsum_kernel<<<dim3(32, 48), 256, 0, stream>>>(Z1f, Z2f, G1f, G2f, Af, S1, S2);
    finalize_kernel<<<64, 256, 0, stream>>>(S1, S2, d1, d2, d3, out);
}

// Round 16
// 52.968 us; speedup vs baseline: 2.2688x; 1.0638x over previous
//
#include <hip/hip_runtime.h>
#include <hip/hip_bf16.h>

#define BN 4096
#define DD 128

// All five bf16 matrices are pre-scaled by SQS = sqrt(2*log2(e)), so the
// MFMA dot product is directly the exp2 argument: 2^(SQS^2 * dot) = e^(2*dot).
#define SQS 1.69864356f

typedef __bf16 bf16x8 __attribute__((ext_vector_type(8)));
typedef float f32x16 __attribute__((ext_vector_type(16)));

__device__ __forceinline__ float fast_exp2(float x) {
    return __builtin_exp2f(x);
}

// ---------------- prep: f32 -> bf16 fragment-major (+gather), diag dots -----
// Fragment-major: per 32-row panel (8192 B), granule g = s*64 + h*32 + r
// holds row r, elements [16s+8h, 16s+8h+8).
__global__ __launch_bounds__(256) void prep_kernel(
    const float* __restrict__ z1, const float* __restrict__ z2,
    const float* __restrict__ attr, const int* __restrict__ uni,
    char* __restrict__ Z1f, char* __restrict__ Z2f,
    char* __restrict__ G1f, char* __restrict__ G2f, char* __restrict__ Af,
    float* __restrict__ d1, float* __restrict__ d2, float* __restrict__ d3,
    float* __restrict__ S1, float* __restrict__ S2, float* __restrict__ out)
{
    int p = blockIdx.x;        // half-panel 0..255 (16 rows each)
    int t = threadIdx.x;       // 0..255
    int gid = p * 256 + t;
    if (gid < 4 * BN) { S1[gid] = 0.f; S2[gid] = 0.f; }
    if (gid == 0) out[0] = 0.f;

    int r = t >> 4, q = t & 15;        // row-in-block (16), col-eighth (8 f32)
    int grow = p * 16 + r;
    int arow = uni[grow];

    __shared__ __hip_bfloat16 lp[5][16][128];

    const float* sp[5] = { z1 + (size_t)grow * DD, z2 + (size_t)grow * DD,
                           z1 + (size_t)arow * DD, z2 + (size_t)arow * DD,
                           attr + (size_t)arow * DD };
    float v[5][8];
    #pragma unroll
    for (int m = 0; m < 5; m++) {
        const float4* s4 = (const float4*)(sp[m] + q * 8);
        #pragma unroll
        for (int i = 0; i < 2; i++) {
            float4 f = s4[i];
            v[m][4*i+0] = f.x; v[m][4*i+1] = f.y;
            v[m][4*i+2] = f.z; v[m][4*i+3] = f.w;
        }
    }
    float p1 = 0.f, p2 = 0.f, p3 = 0.f;
    #pragma unroll
    for (int e = 0; e < 8; e++) {
        p3 += v[0][e] * v[1][e];
        p1 += v[2][e] * v[4][e];
        p2 += v[3][e] * v[4][e];
    }
    #pragma unroll
    for (int m = 1; m < 16; m <<= 1) {
        p1 += __shfl_xor(p1, m);
        p2 += __shfl_xor(p2, m);
        p3 += __shfl_xor(p3, m);
    }
    if (q == 0) { d1[grow] = p1; d2[grow] = p2; d3[grow] = p3; }

    #pragma unroll
    for (int m = 0; m < 5; m++)
        #pragma unroll
        for (int e = 0; e < 8; e++)
            lp[m][r][q * 8 + e] = __float2bfloat16(v[m][e] * SQS);
    __syncthreads();

    int panel = p >> 1, lo = (p & 1) * 16;
    char* dsts[5] = { Z1f, Z2f, G1f, G2f, Af };
    int s = t >> 5, h = (t >> 4) & 1, rl = t & 15;   // granule coords
    int g = s * 64 + h * 32 + lo + rl;
    #pragma unroll
    for (int m = 0; m < 5; m++) {
        bf16x8 val = *reinterpret_cast<const bf16x8*>(&lp[m][rl][s * 16 + h * 8]);
        *reinterpret_cast<bf16x8*>(dsts[m] + (size_t)panel * 8192 + (size_t)g * 16) = val;
    }
}

// ---------------- sweep: free-running waves, global->reg Y stream -----------
// 3072 waves (768 x 4-wave blocks); each wave owns 64 X-rows (xb0/xb1 in
// regs) and a 512-row Y-chunk = 16 fragment-major panels, streamed straight
// from global (L2-resident) into NAMED ping-pong register buffers yA/yB.
// ZERO LDS / ZERO barriers / ZERO DS-pipe usage: waves drift into different
// phases so MFMA, trans(exp), VALU, and L2 overlap across the CU (the 44us
// plateau r2-r15 was these pipes serializing under block-wide phase lockstep;
// pipe-busy fractions summed to ~100%).
// Swapped MFMA operands (A=Y, B=X): Y-rowsum happens inside the accumulate;
// 4 atomicAdds per lane at the end.
// Spill discipline: loop ROLLED (#pragma clang loop unroll(disable)), all
// buffer names static (rule #20), no launch_bounds VGPR cap.  WRITE_SIZE is
// the tripwire (r10/r12 died at full-unroll + dynamic indexing, 0.4-1.8 GB).
__global__ __launch_bounds__(256) void sweep_kernel(
    const char* __restrict__ Z1f, const char* __restrict__ Z2f,
    const char* __restrict__ G1f, const char* __restrict__ G2f,
    const char* __restrict__ Af,
    float* __restrict__ S1, float* __restrict__ S2)
{
    int gwid = blockIdx.x * 4 + (threadIdx.x >> 6);
    int lane = threadIdx.x & 63;
    int r = lane & 31, h = lane >> 5;

    int job, xblk, ychunk;
    const char *X, *Y;
    if (gwid < 1024) {            // jobs 0/1: X=G1f/G2f vs Y=Af (8 chunks)
        job = gwid >> 9;
        int rem = gwid & 511;
        xblk = rem >> 3;          // 0..63
        ychunk = rem & 7;         // 0..7
        X = job ? G2f : G1f;
        Y = Af;
    } else {                      // jobs 2/3: X=Z1f/Z2f vs Y=concat(Z1,Z2)
        int g2 = gwid - 1024;
        job = 2 + (g2 >> 10);
        int rem = g2 & 1023;
        xblk = rem >> 4;          // 0..63
        ychunk = rem & 15;        // 0..15
        X = (job == 2) ? Z1f : Z2f;
        Y = (ychunk < 8) ? Z1f : Z2f;
        ychunk &= 7;
    }

    size_t laneoff = (size_t)(h * 512 + r * 16);

    // X: two 32-row panels (B operand), held in registers for the whole sweep.
    const char* xp = X + (size_t)(xblk * 2) * 8192 + laneoff;
    bf16x8 xb0[8], xb1[8];
    #pragma unroll
    for (int s = 0; s < 8; s++) {
        xb0[s] = *reinterpret_cast<const bf16x8*>(xp + s * 1024);
        xb1[s] = *reinterpret_cast<const bf16x8*>(xp + 8192 + s * 1024);
    }

    float a00 = 0.f, a01 = 0.f;   // X-group 0: sum e, sum e^2
    float a10 = 0.f, a11 = 0.f;   // X-group 1

    bf16x8 yA[8], yB[8];
    const char* ybase = Y + (size_t)ychunk * 512 * 256 + laneoff;

    // panel 0 -> yA
    #pragma unroll
    for (int s = 0; s < 8; s++)
        yA[s] = *reinterpret_cast<const bf16x8*>(ybase + s * 1024);

#define COMPY(BUF)                                                           \
    {                                                                        \
        f32x16 c0, c1;                                                       \
        _Pragma("unroll")                                                    \
        for (int q = 0; q < 16; q++) { c0[q] = 0.f; c1[q] = 0.f; }           \
        _Pragma("unroll")                                                    \
        for (int s = 0; s < 8; s++) {                                        \
            c0 = __builtin_amdgcn_mfma_f32_32x32x16_bf16(BUF[s], xb0[s], c0, 0, 0, 0); \
            c1 = __builtin_amdgcn_mfma_f32_32x32x16_bf16(BUF[s], xb1[s], c1, 0, 0, 0); \
        }                                                                    \
        _Pragma("unroll")                                                    \
        for (int q = 0; q < 16; q++) {                                       \
            float e0 = fast_exp2(c0[q]);                                     \
            a00 += e0;                                                       \
            a01 = fmaf(e0, e0, a01);                                         \
            float e1 = fast_exp2(c1[q]);                                     \
            a10 += e1;                                                       \
            a11 = fmaf(e1, e1, a11);                                         \
        }                                                                    \
    }

    #pragma clang loop unroll(disable)
    for (int it = 0; it < 8; it++) {
        // prefetch odd panel (2it+1) -> yB
        #pragma unroll
        for (int s = 0; s < 8; s++)
            yB[s] = *reinterpret_cast<const bf16x8*>(ybase + 8192 + s * 1024);
        COMPY(yA)                          // compute even panel 2it
        if (it < 7) {                      // prefetch next even panel -> yA
            #pragma unroll
            for (int s = 0; s < 8; s++)
                yA[s] = *reinterpret_cast<const bf16x8*>(ybase + 16384 + s * 1024);
        }
        COMPY(yB)                          // compute odd panel 2it+1
        ybase += 16384;
    }
#undef COMPY

    // Each lane holds partials (its h-half of every panel's Y-rows) for X-row
    // xblk*64 + xg*32 + r; both h lanes atomicAdd disjoint Y contributions.
    {
        int row0 = xblk * 64 + r;
        int row1 = xblk * 64 + 32 + r;
        atomicAdd(&S1[job * BN + row0], a00);
        atomicAdd(&S2[job * BN + row0], a01);
        atomicAdd(&S1[job * BN + row1], a10);
        atomicAdd(&S2[job * BN + row1], a11);
    }
}

// ---------------- finalize: per-row loss terms -> weighted mean --------------
__global__ __launch_bounds__(256) void finalize_kernel(
    const float* __restrict__ S1, const float* __restrict__ S2,
    const float* __restrict__ d1, const float* __restrict__ d2,
    const float* __restrict__ d3, float* __restrict__ out)
{
    int idx = blockIdx.x * 256 + threadIdx.x;   // 0..16383
    float term = 0.f;
    const float EM2 = 0.13533528323661270f;     // e^-2
    if (idx < 8192) {                           // inter jobs 0/1
        int j = idx >> 12, i = idx & 4095;
        float dv = j ? d2[i] : d1[i];
        float n = 4095.f;
        float pos = __expf(2.f * dv);
        float s1 = S1[j * BN + i] - pos;
        float s2 = S2[j * BN + i] - pos * pos;
        float rw = s2 * n / s1;
        float ng = (-0.1f * n * pos + rw) * (1.f / 0.9f);
        ng = fmaxf(ng, n * EM2);
        term = logf((pos + ng) / pos) * (0.5f / 4096.f);
    } else {                                    // intra rows 0..8191
        int i = idx - 8192;
        int ii = i & 4095;
        int job = 2 + (i >> 12);
        float n = 8190.f;
        const float E2 = 7.3890560989306495f, E4 = 54.598150033144236f;
        float pos = __expf(2.f * d3[ii]);
        float s1 = S1[job * BN + ii] - E2 - pos;
        float s2 = S2[job * BN + ii] - E4 - pos * pos;
        float rw = s2 * n / s1;
        float ng = (-0.1f * n * pos + rw) * (1.f / 0.9f);
        ng = fmaxf(ng, n * EM2);
        term = logf((pos + ng) / pos) * (1.f / 8192.f);
    }

    #pragma unroll
    for (int m = 1; m < 64; m <<= 1) term += __shfl_xor(term, m);
    __shared__ float sm[4];
    int wid = threadIdx.x >> 6;
    if ((threadIdx.x & 63) == 0) sm[wid] = term;
    __syncthreads();
    if (threadIdx.x == 0) atomicAdd(out, sm[0] + sm[1] + sm[2] + sm[3]);
}

extern "C" void kernel_launch(void* const* d_in, const int* in_sizes, int n_in,
                              void* d_out, int out_size, void* d_ws, size_t ws_size,
                              hipStream_t stream)
{
    const float* z1   = (const float*)d_in[0];
    const float* z2   = (const float*)d_in[1];
    // d_in[2] = text_z : unused by the reference
    const float* attr = (const float*)d_in[3];
    const int*   uni  = (const int*)d_in[4];
    float* out = (float*)d_out;

    char* ws = (char*)d_ws;
    size_t matb = (size_t)BN * DD * 2;               // bytes per bf16 matrix
    char* Z1f = ws;
    char* Z2f = Z1f + matb;
    char* G1f = Z2f + matb;
    char* G2f = G1f + matb;
    char* Af  = G2f + matb;
    float* S1 = (float*)(ws + 5 * matb);
    float* S2 = S1 + 4 * BN;
    float* d1 = S2 + 4 * BN;
    float* d2 = d1 + BN;
    float* d3 = d2 + BN;

    prep_kernel<<<256, 256, 0, stream>>>(z1, z2, attr, uni,
                                         Z1f, Z2f, G1f, G2f, Af,
                                         d1, d2, d3, S1, S2, out);
    sweep_kernel<<<768, 256, 0, stream>>>(Z1f, Z2f, G1f, G2f, Af, S1, S2);
    finalize_kernel<<<64, 256, 0, stream>>>(S1, S2, d1, d2, d3, out);
}

// Round 17
// 45.173 us; speedup vs baseline: 2.6604x; 1.1726x over previous
//
#include <hip/hip_runtime.h>
#include <hip/hip_bf16.h>

#define BN 4096
#define DD 128

// All five bf16 matrices are pre-scaled by SQS = sqrt(2*log2(e)), so the
// MFMA dot product is directly the exp2 argument: 2^(SQS^2 * dot) = e^(2*dot).
#define SQS 1.69864356f

typedef __bf16 bf16x8 __attribute__((ext_vector_type(8)));
typedef float f32x16 __attribute__((ext_vector_type(16)));

// RAW v_exp_f32 (quarter-rate trans pipe, 1 instruction).  Plain
// __builtin_exp2f without fast-math expands to a guarded multi-instruction
// sequence (~5 extra VALU/exp x 100.7M exps = ~12us of VALU-busy -- the
// r6(33% VALUBusy, 44us) vs r16(54%, 48us) delta).  Inputs here are bounded
// (|arg| < 16), so the raw instruction is safe and accurate.
__device__ __forceinline__ float fast_exp2(float x) {
#if __has_builtin(__builtin_amdgcn_exp2f)
    return __builtin_amdgcn_exp2f(x);
#else
    float r;
    asm("v_exp_f32 %0, %1" : "=v"(r) : "v"(x));
    return r;
#endif
}

// ---------------- prep: f32 -> bf16 fragment-major (+gather), diag dots -----
// Fragment-major: per 32-row panel (8192 B), granule g = s*64 + h*32 + r
// holds row r, elements [16s+8h, 16s+8h+8).
__global__ __launch_bounds__(256) void prep_kernel(
    const float* __restrict__ z1, const float* __restrict__ z2,
    const float* __restrict__ attr, const int* __restrict__ uni,
    char* __restrict__ Z1f, char* __restrict__ Z2f,
    char* __restrict__ G1f, char* __restrict__ G2f, char* __restrict__ Af,
    float* __restrict__ d1, float* __restrict__ d2, float* __restrict__ d3,
    float* __restrict__ S1, float* __restrict__ S2, float* __restrict__ out)
{
    int p = blockIdx.x;        // half-panel 0..255 (16 rows each)
    int t = threadIdx.x;       // 0..255
    int gid = p * 256 + t;
    if (gid < 4 * BN) { S1[gid] = 0.f; S2[gid] = 0.f; }
    if (gid == 0) out[0] = 0.f;

    int r = t >> 4, q = t & 15;        // row-in-block (16), col-eighth (8 f32)
    int grow = p * 16 + r;
    int arow = uni[grow];

    __shared__ __hip_bfloat16 lp[5][16][128];

    const float* sp[5] = { z1 + (size_t)grow * DD, z2 + (size_t)grow * DD,
                           z1 + (size_t)arow * DD, z2 + (size_t)arow * DD,
                           attr + (size_t)arow * DD };
    float v[5][8];
    #pragma unroll
    for (int m = 0; m < 5; m++) {
        const float4* s4 = (const float4*)(sp[m] + q * 8);
        #pragma unroll
        for (int i = 0; i < 2; i++) {
            float4 f = s4[i];
            v[m][4*i+0] = f.x; v[m][4*i+1] = f.y;
            v[m][4*i+2] = f.z; v[m][4*i+3] = f.w;
        }
    }
    float p1 = 0.f, p2 = 0.f, p3 = 0.f;
    #pragma unroll
    for (int e = 0; e < 8; e++) {
        p3 += v[0][e] * v[1][e];
        p1 += v[2][e] * v[4][e];
        p2 += v[3][e] * v[4][e];
    }
    #pragma unroll
    for (int m = 1; m < 16; m <<= 1) {
        p1 += __shfl_xor(p1, m);
        p2 += __shfl_xor(p2, m);
        p3 += __shfl_xor(p3, m);
    }
    if (q == 0) { d1[grow] = p1; d2[grow] = p2; d3[grow] = p3; }

    #pragma unroll
    for (int m = 0; m < 5; m++)
        #pragma unroll
        for (int e = 0; e < 8; e++)
            lp[m][r][q * 8 + e] = __float2bfloat16(v[m][e] * SQS);
    __syncthreads();

    int panel = p >> 1, lo = (p & 1) * 16;
    char* dsts[5] = { Z1f, Z2f, G1f, G2f, Af };
    int s = t >> 5, h = (t >> 4) & 1, rl = t & 15;   // granule coords
    int g = s * 64 + h * 32 + lo + rl;
    #pragma unroll
    for (int m = 0; m < 5; m++) {
        bf16x8 val = *reinterpret_cast<const bf16x8*>(&lp[m][rl][s * 16 + h * 8]);
        *reinterpret_cast<bf16x8*>(dsts[m] + (size_t)panel * 8192 + (size_t)g * 16) = val;
    }
}

// ---------------- sweep: free-running waves, global->reg Y stream -----------
// 3072 waves (768 x 4-wave blocks); each wave owns 64 X-rows (xb0/xb1 in
// regs) and a 512-row Y-chunk = 16 fragment-major panels, streamed straight
// from global (L2-resident) into NAMED ping-pong register buffers yA/yB.
// ZERO LDS / ZERO barriers / ZERO DS-pipe usage.  Swapped MFMA operands
// (A=Y, B=X): Y-rowsum happens inside the accumulate; 4 atomicAdds/lane.
// Spill discipline: loop ROLLED, all buffer names static (rule #20), no
// launch_bounds VGPR cap.  WRITE_SIZE is the spill tripwire.
__global__ __launch_bounds__(256) void sweep_kernel(
    const char* __restrict__ Z1f, const char* __restrict__ Z2f,
    const char* __restrict__ G1f, const char* __restrict__ G2f,
    const char* __restrict__ Af,
    float* __restrict__ S1, float* __restrict__ S2)
{
    int gwid = blockIdx.x * 4 + (threadIdx.x >> 6);
    int lane = threadIdx.x & 63;
    int r = lane & 31, h = lane >> 5;

    int job, xblk, ychunk;
    const char *X, *Y;
    if (gwid < 1024) {            // jobs 0/1: X=G1f/G2f vs Y=Af (8 chunks)
        job = gwid >> 9;
        int rem = gwid & 511;
        xblk = rem >> 3;          // 0..63
        ychunk = rem & 7;         // 0..7
        X = job ? G2f : G1f;
        Y = Af;
    } else {                      // jobs 2/3: X=Z1f/Z2f vs Y=concat(Z1,Z2)
        int g2 = gwid - 1024;
        job = 2 + (g2 >> 10);
        int rem = g2 & 1023;
        xblk = rem >> 4;          // 0..63
        ychunk = rem & 15;        // 0..15
        X = (job == 2) ? Z1f : Z2f;
        Y = (ychunk < 8) ? Z1f : Z2f;
        ychunk &= 7;
    }

    size_t laneoff = (size_t)(h * 512 + r * 16);

    // X: two 32-row panels (B operand), held in registers for the whole sweep.
    const char* xp = X + (size_t)(xblk * 2) * 8192 + laneoff;
    bf16x8 xb0[8], xb1[8];
    #pragma unroll
    for (int s = 0; s < 8; s++) {
        xb0[s] = *reinterpret_cast<const bf16x8*>(xp + s * 1024);
        xb1[s] = *reinterpret_cast<const bf16x8*>(xp + 8192 + s * 1024);
    }

    float a00 = 0.f, a01 = 0.f;   // X-group 0: sum e, sum e^2
    float a10 = 0.f, a11 = 0.f;   // X-group 1

    bf16x8 yA[8], yB[8];
    const char* ybase = Y + (size_t)ychunk * 512 * 256 + laneoff;

    // panel 0 -> yA
    #pragma unroll
    for (int s = 0; s < 8; s++)
        yA[s] = *reinterpret_cast<const bf16x8*>(ybase + s * 1024);

#define COMPY(BUF)                                                           \
    {                                                                        \
        f32x16 c0, c1;                                                       \
        _Pragma("unroll")                                                    \
        for (int q = 0; q < 16; q++) { c0[q] = 0.f; c1[q] = 0.f; }           \
        _Pragma("unroll")                                                    \
        for (int s = 0; s < 8; s++) {                                        \
            c0 = __builtin_amdgcn_mfma_f32_32x32x16_bf16(BUF[s], xb0[s], c0, 0, 0, 0); \
            c1 = __builtin_amdgcn_mfma_f32_32x32x16_bf16(BUF[s], xb1[s], c1, 0, 0, 0); \
        }                                                                    \
        _Pragma("unroll")                                                    \
        for (int q = 0; q < 16; q++) {                                       \
            float e0 = fast_exp2(c0[q]);                                     \
            a00 += e0;                                                       \
            a01 = fmaf(e0, e0, a01);                                         \
            float e1 = fast_exp2(c1[q]);                                     \
            a10 += e1;                                                       \
            a11 = fmaf(e1, e1, a11);                                         \
        }                                                                    \
    }

    #pragma clang loop unroll(disable)
    for (int it = 0; it < 8; it++) {
        // prefetch odd panel (2it+1) -> yB
        #pragma unroll
        for (int s = 0; s < 8; s++)
            yB[s] = *reinterpret_cast<const bf16x8*>(ybase + 8192 + s * 1024);
        COMPY(yA)                          // compute even panel 2it
        if (it < 7) {                      // prefetch next even panel -> yA
            #pragma unroll
            for (int s = 0; s < 8; s++)
                yA[s] = *reinterpret_cast<const bf16x8*>(ybase + 16384 + s * 1024);
        }
        COMPY(yB)                          // compute odd panel 2it+1
        ybase += 16384;
    }
#undef COMPY

    // Each lane holds partials (its h-half of every panel's Y-rows) for X-row
    // xblk*64 + xg*32 + r; both h lanes atomicAdd disjoint Y contributions.
    {
        int row0 = xblk * 64 + r;
        int row1 = xblk * 64 + 32 + r;
        atomicAdd(&S1[job * BN + row0], a00);
        atomicAdd(&S2[job * BN + row0], a01);
        atomicAdd(&S1[job * BN + row1], a10);
        atomicAdd(&S2[job * BN + row1], a11);
    }
}

// ---------------- finalize: per-row loss terms -> weighted mean --------------
__global__ __launch_bounds__(256) void finalize_kernel(
    const float* __restrict__ S1, const float* __restrict__ S2,
    const float* __restrict__ d1, const float* __restrict__ d2,
    const float* __restrict__ d3, float* __restrict__ out)
{
    int idx = blockIdx.x * 256 + threadIdx.x;   // 0..16383
    float term = 0.f;
    const float EM2 = 0.13533528323661270f;     // e^-2
    if (idx < 8192) {                           // inter jobs 0/1
        int j = idx >> 12, i = idx & 4095;
        float dv = j ? d2[i] : d1[i];
        float n = 4095.f;
        float pos = __expf(2.f * dv);
        float s1 = S1[j * BN + i] - pos;
        float s2 = S2[j * BN + i] - pos * pos;
        float rw = s2 * n / s1;
        float ng = (-0.1f * n * pos + rw) * (1.f / 0.9f);
        ng = fmaxf(ng, n * EM2);
        term = logf((pos + ng) / pos) * (0.5f / 4096.f);
    } else {                                    // intra rows 0..8191
        int i = idx - 8192;
        int ii = i & 4095;
        int job = 2 + (i >> 12);
        float n = 8190.f;
        const float E2 = 7.3890560989306495f, E4 = 54.598150033144236f;
        float pos = __expf(2.f * d3[ii]);
        float s1 = S1[job * BN + ii] - E2 - pos;
        float s2 = S2[job * BN + ii] - E4 - pos * pos;
        float rw = s2 * n / s1;
        float ng = (-0.1f * n * pos + rw) * (1.f / 0.9f);
        ng = fmaxf(ng, n * EM2);
        term = logf((pos + ng) / pos) * (1.f / 8192.f);
    }

    #pragma unroll
    for (int m = 1; m < 64; m <<= 1) term += __shfl_xor(term, m);
    __shared__ float sm[4];
    int wid = threadIdx.x >> 6;
    if ((threadIdx.x & 63) == 0) sm[wid] = term;
    __syncthreads();
    if (threadIdx.x == 0) atomicAdd(out, sm[0] + sm[1] + sm[2] + sm[3]);
}

extern "C" void kernel_launch(void* const* d_in, const int* in_sizes, int n_in,
                              void* d_out, int out_size, void* d_ws, size_t ws_size,
                              hipStream_t stream)
{
    const float* z1   = (const float*)d_in[0];
    const float* z2   = (const float*)d_in[1];
    // d_in[2] = text_z : unused by the reference
    const float* attr = (const float*)d_in[3];
    const int*   uni  = (const int*)d_in[4];
    float* out = (float*)d_out;

    char* ws = (char*)d_ws;
    size_t matb = (size_t)BN * DD * 2;               // bytes per bf16 matrix
    char* Z1f = ws;
    char* Z2f = Z1f + matb;
    char* G1f = Z2f + matb;
    char* G2f = G1f + matb;
    char* Af  = G2f + matb;
    float* S1 = (float*)(ws + 5 * matb);
    float* S2 = S1 + 4 * BN;
    float* d1 = S2 + 4 * BN;
    float* d2 = d1 + BN;
    float* d3 = d2 + BN;

    prep_kernel<<<256, 256, 0, stream>>>(z1, z2, attr, uni,
                                         Z1f, Z2f, G1f, G2f, Af,
                                         d1, d2, d3, S1, S2, out);
    sweep_kernel<<<768, 256, 0, stream>>>(Z1f, Z2f, G1f, G2f, Af, S1, S2);
    finalize_kernel<<<64, 256, 0, stream>>>(S1, S2, d1, d2, d3, out);
}